// Round 14
// baseline (331.174 us; speedup 1.0000x reference)
//
#include <hip/hip_runtime.h>
#include <hip/hip_cooperative_groups.h>
#include <math.h>

namespace cg = cooperative_groups;

#define NGRAPH 32
#define CAP 10240        // edge capacity per dst bucket (mean 8192, +22 sigma)
#define BT 1024
#define GRID 256
#define EPT 8            // edges per thread in part phase
#define EPB (BT * EPT)   // 8192 edges per part tile

__global__ __launch_bounds__(BT, 4) void k_fused(
    const int* __restrict__ src, const int* __restrict__ dst,
    const float* __restrict__ x, const int* __restrict__ batch,
    const float* __restrict__ lin_w, const float* __restrict__ lin_b,
    const float* __restrict__ gcn_w, const float* __restrict__ gcn_b,
    const float* __restrict__ r1_w, const float* __restrict__ r1_b,
    const float* __restrict__ r2_w, const float* __restrict__ r2_b,
    float* __restrict__ out,
    unsigned int* __restrict__ packed, unsigned short* __restrict__ csr,
    int* __restrict__ offs, int* __restrict__ deg,
    float* __restrict__ dinv, float2* __restrict__ q0, float2* __restrict__ q1,
    float2* __restrict__ q2, float2* __restrict__ p3,
    int* __restrict__ gcursor, float* __restrict__ S, float* __restrict__ chainv,
    int N, int E)
{
    cg::grid_group grid = cg::this_grid();
    __shared__ unsigned int ldsbuf[EPB];                 // 32 KB (part stage / chain partials / readout scratch)
    __shared__ int h0[256], h1[256], h2[256], h3[256];   // 4 KB
    __shared__ float fbuf[640];                          // 2.5 KB

    const int tid = threadIdx.x;
    const int b = blockIdx.x;
    const int NB = (N + 255) >> 8;                       // 196
    const int ntiles = (E + EPB - 1) / EPB;              // 196
    const int nvb = (N + 63) >> 6;                       // 782 hop groups of 64 nodes

    // ---------------- P0: zero gcursor + S ----------------
    if (b == 0) {
        if (tid < 256) gcursor[tid] = 0;
        else if (tid < 320) S[tid - 256] = 0.f;
    }
    grid.sync();

    // ---------------- P1: partition edges into bucket ranges ----------------
    if (b < ntiles) {
        int e0 = b * EPB;
        if (tid < 256) h0[tid] = 0;                      // hist
        __syncthreads();
        int d[EPT], s[EPT];
#pragma unroll
        for (int c = 0; c < EPT / 4; c++) {
            int e = e0 + c * 4096 + (tid << 2);
            if (e + 3 < E) {
                int4 dv = *(const int4*)&dst[e];
                int4 sv = *(const int4*)&src[e];
                d[4*c+0] = dv.x; d[4*c+1] = dv.y; d[4*c+2] = dv.z; d[4*c+3] = dv.w;
                s[4*c+0] = sv.x; s[4*c+1] = sv.y; s[4*c+2] = sv.z; s[4*c+3] = sv.w;
                atomicAdd(&h0[dv.x >> 8], 1);
                atomicAdd(&h0[dv.y >> 8], 1);
                atomicAdd(&h0[dv.z >> 8], 1);
                atomicAdd(&h0[dv.w >> 8], 1);
            } else {
#pragma unroll
                for (int k = 0; k < 4; k++) {
                    int ee = e + k;
                    if (ee < E) {
                        d[4*c+k] = dst[ee]; s[4*c+k] = src[ee];
                        atomicAdd(&h0[d[4*c+k] >> 8], 1);
                    } else {
                        d[4*c+k] = -1;
                    }
                }
            }
        }
        __syncthreads();
        int v = 0;
        if (tid < 256) { v = h0[tid]; h1[tid] = v; }
        __syncthreads();
        for (int off = 1; off < 256; off <<= 1) {
            int t = 0;
            if (tid < 256 && tid >= off) t = h1[tid - off];
            __syncthreads();
            if (tid < 256) h1[tid] += t;
            __syncthreads();
        }
        int total = h1[255];
        __syncthreads();
        if (tid < 256) {
            int excl = h1[tid] - v;
            h1[tid] = excl;                              // lofs
            h2[tid] = excl;                              // lcur
            if (v > 0) h3[tid] = tid * CAP + atomicAdd(&gcursor[tid], v);  // base
        }
        __syncthreads();
#pragma unroll
        for (int c = 0; c < EPT; c++) {
            int dd = d[c];
            if (dd >= 0) {
                int bk = dd >> 8;
                int slot = atomicAdd(&h2[bk], 1);
                ldsbuf[slot] = ((unsigned int)bk << 24) | ((unsigned int)s[c] << 8)
                             | (unsigned int)(dd & 255);
            }
        }
        __syncthreads();
        for (int i = tid; i < total; i += BT) {
            unsigned int wv = ldsbuf[i];
            int bk = wv >> 24;
            packed[h3[bk] + (i - h1[bk])] = wv & 0xFFFFFFu;
        }
    }
    grid.sync();

    // ---------------- P2: per-bucket CSR build (+deg/dinv/q0/counts); chain on block NB ----------------
    if (b < NB) {
        int start = b * CAP;
        int end = start + gcursor[b];
        if (tid < 256) h0[tid] = 0;                      // cnt
        if (tid < NGRAPH) fbuf[tid] = 0.f;               // cs
        __syncthreads();
        for (int e = start + tid; e < end; e += BT)
            atomicAdd(&h0[packed[e] & 255], 1);
        __syncthreads();
        int v = 0, vp = 0;
        if (tid < 256) {
            v = h0[tid];
            vp = (v + 1) & ~1;                           // even-pad per node
            h1[tid] = vp;
        }
        __syncthreads();
        for (int off = 1; off < 256; off <<= 1) {
            int t = 0;
            if (tid < 256 && tid >= off) t = h1[tid - off];
            __syncthreads();
            if (tid < 256) h1[tid] += t;
            __syncthreads();
        }
        if (tid < 256) {
            int excl = h1[tid] - vp;
            h2[tid] = excl;                              // lcur
            int node = b * 256 + tid;
            if (node < N) {
                deg[node] = v;
                offs[node] = start + excl;
                float dv = rsqrtf((float)(v + 1));       // +1 self loop
                dinv[node] = dv;
                q0[node] = make_float2(x[node] * dv, dv);
                atomicAdd(&fbuf[batch[node]], 1.f);
            }
        }
        __syncthreads();
        for (int e = start + tid; e < end; e += BT) {
            unsigned int p = packed[e];
            int pos = start + atomicAdd(&h2[p & 255], 1);
            csr[pos] = (unsigned short)(p >> 8);
        }
        if (tid < NGRAPH && fbuf[tid] != 0.f) atomicAdd(&S[tid], fbuf[tid]);
    } else if (b == NB) {
        // chain: va=lin_w W1W2W3, vb=lin_b W1W2W3, vc=b1 W2W3, vd=b2 W3
        float* v4 = fbuf;                                // 512 floats
        float* ch = (float*)ldsbuf;                      // 4096 partials (16 KB)
        if (tid < 128) {
            v4[tid]       = lin_w[tid];
            v4[128 + tid] = lin_b[tid];
            v4[256 + tid] = gcn_b[tid];                  // b1
            v4[384 + tid] = gcn_b[128 + tid];            // b2
        }
        int j = tid & 127, kh = tid >> 7;                // kh 0..7
        for (int l = 0; l < 3; l++) {
            __syncthreads();
            const float* W = gcn_w + l * 128 * 128;
            float na = 0.f, nb = 0.f, nc = 0.f, nd = 0.f;
#pragma unroll
            for (int kk = 0; kk < 16; kk++) {
                int k = kh * 16 + kk;
                float w = W[k * 128 + j];                // coalesced across j
                na += v4[k] * w;
                nb += v4[128 + k] * w;
                nc += v4[256 + k] * w;
                nd += v4[384 + k] * w;
            }
            ch[(0 * 128 + j) * 8 + kh] = na;
            ch[(1 * 128 + j) * 8 + kh] = nb;
            ch[(2 * 128 + j) * 8 + kh] = nc;
            ch[(3 * 128 + j) * 8 + kh] = nd;
            __syncthreads();
            if (tid < 512) {
                int vec = tid >> 7, jj = tid & 127;
                float s = 0.f;
#pragma unroll
                for (int c = 0; c < 8; c++) s += ch[(vec * 128 + jj) * 8 + c];
                if (vec < 2 || (vec == 2 && l >= 1) || (vec == 3 && l >= 2))
                    v4[vec * 128 + jj] = s;
            }
        }
        __syncthreads();
        if (tid < 512) chainv[tid] = v4[tid];
    }
    grid.sync();

    // ---------------- P3-5: hops (gather, 16 lanes/node, 64 nodes/block-iter) ----------------
#pragma unroll
    for (int l = 0; l < 3; l++) {
        const float2* qin = (l == 0) ? q0 : (l == 1) ? q1 : q2;
        float2* outv      = (l == 0) ? q1 : (l == 1) ? q2 : p3;
        int lane = tid & 15;
        int sub = tid >> 4;                              // 0..63
        for (int vb = b; vb < nvb; vb += GRID) {
            int node = vb * 64 + sub;
            if (node < N) {
                int e = offs[node], ne = deg[node];      // e even
                float sx = 0.f, su = 0.f;
                for (int j = 2 * lane; j < ne; j += 32) {
                    ushort2 c = *(const ushort2*)&csr[e + j];
                    float2 a = qin[c.x];
                    sx += a.x; su += a.y;
                    if (j + 1 < ne) {
                        float2 bb = qin[c.y];
                        sx += bb.x; su += bb.y;
                    }
                }
#pragma unroll
                for (int m = 8; m > 0; m >>= 1) {
                    sx += __shfl_xor(sx, m);
                    su += __shfl_xor(su, m);
                }
                if (lane == 0) {
                    float2 qs = qin[node];
                    float dv = dinv[node];
                    float px = dv * (sx + qs.x), pu = dv * (su + qs.y);
                    if (l < 2) outv[node] = make_float2(px * dv, pu * dv);
                    else       outv[node] = make_float2(px, pu);
                }
            }
        }
        grid.sync();
    }

    // ---------------- P6: readout (per-graph sums + MLP), blocks 0..31 ----------------
    if (b < NGRAPH) {
        int g = b;
        float* f    = (float*)ldsbuf;
        float* cnts = f;               // 32
        float* rsum = f + 32;          // 64 (16 waves x 4)
        float* pl   = f + 96;          // 128
        float* mm   = f + 224;         // 1024
        float* red  = f + 1248;        // 128
        if (tid < NGRAPH) cnts[tid] = S[tid];
        __syncthreads();
        int r0 = 0;
        for (int i = 0; i < g; i++) r0 += (int)cnts[i];
        int cnt = (int)cnts[g];
        int r1 = r0 + cnt;
        float su1 = 0.f, su2 = 0.f, su3 = 0.f, sv3 = 0.f;
        for (int n = r0 + tid; n < r1; n += BT) {
            float inv = 1.0f / dinv[n];
            su1 += q1[n].y * inv;
            su2 += q2[n].y * inv;
            float2 p = p3[n];
            su3 += p.y; sv3 += p.x;
        }
#pragma unroll
        for (int m = 32; m > 0; m >>= 1) {
            su1 += __shfl_xor(su1, m);
            su2 += __shfl_xor(su2, m);
            su3 += __shfl_xor(su3, m);
            sv3 += __shfl_xor(sv3, m);
        }
        int wv = tid >> 6;                               // 0..15
        if ((tid & 63) == 0) {
            rsum[wv] = su1; rsum[16 + wv] = su2; rsum[32 + wv] = su3; rsum[48 + wv] = sv3;
        }
        __syncthreads();
        su1 = 0.f; su2 = 0.f; su3 = 0.f; sv3 = 0.f;
#pragma unroll
        for (int i = 0; i < 16; i++) {
            su1 += rsum[i]; su2 += rsum[16 + i]; su3 += rsum[32 + i]; sv3 += rsum[48 + i];
        }
        const float* b3 = gcn_b + 2 * 128;
        if (tid < 128)
            pl[tid] = sv3 * chainv[tid] + su3 * chainv[128 + tid] + su2 * chainv[256 + tid]
                    + su1 * chainv[384 + tid] + (float)cnt * b3[tid];
        __syncthreads();
        int j = tid & 127, ck = tid >> 7;                // ck 0..7
        float acc = 0.f;
#pragma unroll
        for (int kk = 0; kk < 16; kk++) {
            int k = ck * 16 + kk;
            acc += pl[k] * r1_w[k * 128 + j];            // coalesced across j
        }
        mm[ck * 128 + j] = acc;
        __syncthreads();
        if (tid < 128) {
            float a = r1_b[tid];
#pragma unroll
            for (int c = 0; c < 8; c++) a += mm[c * 128 + tid];
            red[tid] = tanhf(a) * r2_w[tid];
        }
        __syncthreads();
        for (int sft = 64; sft > 0; sft >>= 1) {
            if (tid < sft) red[tid] += red[tid + sft];
            __syncthreads();
        }
        if (tid == 0) out[g] = red[0] + r2_b[0];
    }
}

extern "C" void kernel_launch(void* const* d_in, const int* in_sizes, int n_in,
                              void* d_out, int out_size, void* d_ws, size_t ws_size,
                              hipStream_t stream) {
    const float* x     = (const float*)d_in[0];
    const int*   eidx  = (const int*)d_in[1];
    const int*   batch = (const int*)d_in[2];
    const float* lin_w = (const float*)d_in[3];
    const float* lin_b = (const float*)d_in[4];
    const float* gcn_w = (const float*)d_in[5];
    const float* gcn_b = (const float*)d_in[6];
    const float* r1_w  = (const float*)d_in[7];
    const float* r1_b  = (const float*)d_in[8];
    const float* r2_w  = (const float*)d_in[9];
    const float* r2_b  = (const float*)d_in[10];

    int N = in_sizes[0];
    int E = in_sizes[1] / 2;
    const int* src = eidx;
    const int* dst = eidx + E;

    // workspace layout: 8B-aligned first, then 4B, then 2B csr
    char* w = (char*)d_ws;
    float2* q0      = (float2*)w; w += (size_t)N * 8;
    float2* q1      = (float2*)w; w += (size_t)N * 8;
    float2* q2      = (float2*)w; w += (size_t)N * 8;
    float2* p3      = (float2*)w; w += (size_t)N * 8;
    unsigned int* packed = (unsigned int*)w; w += (size_t)256 * CAP * 4;
    int*    offs    = (int*)w;    w += (size_t)N * 4;
    int*    deg     = (int*)w;    w += (size_t)N * 4;
    float*  dinv    = (float*)w;  w += (size_t)N * 4;
    int*    gcursor = (int*)w;    w += 256 * 4;
    float*  S       = (float*)w;  w += 64 * 4;
    float*  chainv  = (float*)w;  w += 512 * 4;
    unsigned short* csr = (unsigned short*)w; w += (size_t)256 * CAP * 2 + 256;

    float* outp = (float*)d_out;

    void* args[] = {
        (void*)&src, (void*)&dst, (void*)&x, (void*)&batch,
        (void*)&lin_w, (void*)&lin_b, (void*)&gcn_w, (void*)&gcn_b,
        (void*)&r1_w, (void*)&r1_b, (void*)&r2_w, (void*)&r2_b,
        (void*)&outp, (void*)&packed, (void*)&csr,
        (void*)&offs, (void*)&deg, (void*)&dinv,
        (void*)&q0, (void*)&q1, (void*)&q2, (void*)&p3,
        (void*)&gcursor, (void*)&S, (void*)&chainv,
        (void*)&N, (void*)&E
    };
    hipLaunchCooperativeKernel((const void*)k_fused, dim3(GRID), dim3(BT),
                               args, 0, stream);
}

// Round 15
// 162.569 us; speedup vs baseline: 2.0371x; 2.0371x over previous
//
#include <hip/hip_runtime.h>
#include <hip/hip_bf16.h>
#include <math.h>

#define NGRAPH 32
#define CAP 10240        // edge capacity per bucket (mean 8192, +22 sigma)
#define EPT 24           // edges per thread in k_part
#define EPB (256 * EPT)  // 6144 edges per partition block

// ---------------- partition edges into fixed-capacity bucket ranges ----------------
// staged word: (bucket << 24) | (src << 8) | (dst & 255)   [src < 65536]
__global__ void k_part(const int* __restrict__ src, const int* __restrict__ dst,
                       int* __restrict__ gcursor, unsigned int* __restrict__ packed, int E) {
    __shared__ unsigned int ldsbuf[EPB];          // 24 KB
    __shared__ int hist[256], lofs[256], lcur[256], base[256];
    int tid = threadIdx.x;
    int e0 = blockIdx.x * EPB;
    hist[tid] = 0;
    __syncthreads();
    int d[EPT], s[EPT];
#pragma unroll
    for (int c = 0; c < EPT / 4; c++) {
        int e = e0 + c * 1024 + (tid << 2);
        if (e + 3 < E) {
            int4 dv = *(const int4*)&dst[e];
            int4 sv = *(const int4*)&src[e];
            d[4*c+0] = dv.x; d[4*c+1] = dv.y; d[4*c+2] = dv.z; d[4*c+3] = dv.w;
            s[4*c+0] = sv.x; s[4*c+1] = sv.y; s[4*c+2] = sv.z; s[4*c+3] = sv.w;
            atomicAdd(&hist[dv.x >> 8], 1);
            atomicAdd(&hist[dv.y >> 8], 1);
            atomicAdd(&hist[dv.z >> 8], 1);
            atomicAdd(&hist[dv.w >> 8], 1);
        } else {
#pragma unroll
            for (int k = 0; k < 4; k++) {
                int ee = e + k;
                if (ee < E) {
                    d[4*c+k] = dst[ee]; s[4*c+k] = src[ee];
                    atomicAdd(&hist[d[4*c+k] >> 8], 1);
                } else {
                    d[4*c+k] = -1;
                }
            }
        }
    }
    __syncthreads();
    int v = hist[tid];
    lofs[tid] = v;
    __syncthreads();
    for (int off = 1; off < 256; off <<= 1) {
        int t = (tid >= off) ? lofs[tid - off] : 0;
        __syncthreads();
        lofs[tid] += t;
        __syncthreads();
    }
    int total = lofs[255];
    int excl = lofs[tid] - v;
    lofs[tid] = excl;
    lcur[tid] = excl;
    if (v > 0) base[tid] = tid * CAP + atomicAdd(&gcursor[tid], v);
    __syncthreads();
#pragma unroll
    for (int c = 0; c < EPT; c++) {
        int dd = d[c];
        if (dd >= 0) {
            int bk = dd >> 8;
            int slot = atomicAdd(&lcur[bk], 1);
            ldsbuf[slot] = ((unsigned int)bk << 24) | ((unsigned int)s[c] << 8)
                         | (unsigned int)(dd & 255);
        }
    }
    __syncthreads();
    for (int i = tid; i < total; i += 256) {
        unsigned int w = ldsbuf[i];
        int bk = w >> 24;
        packed[base[bk] + (i - lofs[bk])] = w & 0xFFFFFFu;
    }
}

// ---------------- per-bucket CSR build (even-padded, sentinel-filled) + deg/dinv/q0/counts ----------------
__global__ void k_bucket(const unsigned int* __restrict__ packed, const int* __restrict__ gcursor,
                         const float* __restrict__ x, const int* __restrict__ batch,
                         int* __restrict__ offs, int* __restrict__ deg,
                         float* __restrict__ dinv, float2* __restrict__ q0,
                         float2* __restrict__ q1, float2* __restrict__ q2,
                         unsigned short* __restrict__ csr, float* __restrict__ S, int N) {
    __shared__ int cnt[256], lofs[256], lcur[256];
    __shared__ float cs[NGRAPH];
    int tid = threadIdx.x;
    int b = blockIdx.x;
    int start = b * CAP;
    int end = start + gcursor[b];
    cnt[tid] = 0;
    if (tid < NGRAPH) cs[tid] = 0.f;
    __syncthreads();
    for (int e = start + tid; e < end; e += 256)
        atomicAdd(&cnt[packed[e] & 255], 1);
    __syncthreads();
    int v = cnt[tid];
    int vp = (v + 1) & ~1;          // pad each node's slot to even length
    lofs[tid] = vp;
    __syncthreads();
    for (int off = 1; off < 256; off <<= 1) {
        int t = (tid >= off) ? lofs[tid - off] : 0;
        __syncthreads();
        lofs[tid] += t;
        __syncthreads();
    }
    int excl = lofs[tid] - vp;      // even for every node
    lcur[tid] = excl;
    int node = b * 256 + tid;
    if (node < N) {
        deg[node] = v;
        offs[node] = start + excl;
        float dv = rsqrtf((float)(v + 1));   // +1 self loop
        dinv[node] = dv;
        q0[node] = make_float2(x[node] * dv, dv);
        atomicAdd(&cs[batch[node]], 1.f);
        if (v & 1) csr[start + excl + v] = (unsigned short)N;  // sentinel pad -> q[N]=(0,0)
    }
    if (b == 0 && tid == 0) {
        q0[N] = make_float2(0.f, 0.f);
        q1[N] = make_float2(0.f, 0.f);
        q2[N] = make_float2(0.f, 0.f);
    }
    __syncthreads();
    for (int e = start + tid; e < end; e += 256) {
        unsigned int p = packed[e];
        int pos = start + atomicAdd(&lcur[p & 255], 1);
        csr[pos] = (unsigned short)(p >> 8);
    }
    if (tid < NGRAPH && cs[tid] != 0.f) atomicAdd(&S[tid], cs[tid]);
}

// ---------------- one hop, 16 lanes per node, ushort2 csr loads, no tail branch ----------------
template <int WRITE_Q>
__global__ void k_hop(const float2* __restrict__ qin, float2* __restrict__ outv,
                      const unsigned short* __restrict__ csr,
                      const int* __restrict__ offs, const int* __restrict__ deg,
                      const float* __restrict__ dinv, int N) {
    int tid = threadIdx.x;
    int lane = tid & 15;
    int node = blockIdx.x * 16 + (tid >> 4);
    if (node >= N) return;
    int e = offs[node], ne = deg[node];   // e even; slot even-padded with sentinel
    float sx = 0.0f, su = 0.0f;
    for (int j = 2 * lane; j < ne; j += 32) {
        ushort2 c = *(const ushort2*)&csr[e + j];   // pad entry -> qin[N] == (0,0)
        float2 a = qin[c.x];
        float2 b = qin[c.y];
        sx += a.x + b.x;
        su += a.y + b.y;
    }
#pragma unroll
    for (int m = 8; m > 0; m >>= 1) {
        sx += __shfl_xor(sx, m);
        su += __shfl_xor(su, m);
    }
    if (lane == 0) {
        float2 qs = qin[node];
        float dv = dinv[node];
        float px = dv * (sx + qs.x), pu = dv * (su + qs.y);
        if (WRITE_Q) outv[node] = make_float2(px * dv, pu * dv);
        else         outv[node] = make_float2(px, pu);
    }
}

// ---------------- chain weight vectors, LDS-staged W (1 block x 1024 thr) ----------------
__global__ __launch_bounds__(1024) void k_chain(
        const float* __restrict__ lin_w, const float* __restrict__ lin_b,
        const float* __restrict__ gcn_w, const float* __restrict__ gcn_b,
        float* __restrict__ chainv) {
    __shared__ float W[128 * 128];        // 64 KB
    __shared__ float v4[4 * 128];
    __shared__ float part[4 * 128 * 8];   // 16 KB
    int tid = threadIdx.x;
    int j = tid & 127;
    int ch = tid >> 7;                    // 0..7
    if (tid < 128) {
        v4[tid]       = lin_w[tid];
        v4[128 + tid] = lin_b[tid];
        v4[256 + tid] = gcn_b[tid];        // b1
        v4[384 + tid] = gcn_b[128 + tid];  // b2
    }
    for (int l = 0; l < 3; l++) {
        __syncthreads();
        const float4* Wg = (const float4*)(gcn_w + l * 128 * 128);
        float4* Ws = (float4*)W;
#pragma unroll
        for (int i = 0; i < 4; i++) Ws[tid + i * 1024] = Wg[tid + i * 1024];
        __syncthreads();
        float na = 0.f, nb = 0.f, nc = 0.f, nd = 0.f;
#pragma unroll
        for (int kk = 0; kk < 16; kk++) {
            int k = ch * 16 + kk;
            float w = W[k * 128 + j];
            na += v4[k] * w;
            nb += v4[128 + k] * w;
            nc += v4[256 + k] * w;
            nd += v4[384 + k] * w;
        }
        part[(0 * 128 + j) * 8 + ch] = na;
        part[(1 * 128 + j) * 8 + ch] = nb;
        part[(2 * 128 + j) * 8 + ch] = nc;
        part[(3 * 128 + j) * 8 + ch] = nd;
        __syncthreads();
        if (tid < 512) {
            int vec = tid >> 7, jj = tid & 127;
            float s = 0.f;
#pragma unroll
            for (int c = 0; c < 8; c++) s += part[(vec * 128 + jj) * 8 + c];
            if (vec < 2 || (vec == 2 && l >= 1) || (vec == 3 && l >= 2))
                v4[vec * 128 + jj] = s;
        }
    }
    __syncthreads();
    if (tid < 512) chainv[tid] = v4[tid];
}

// ---------------- readout: per-graph sums + MLP, LDS-staged r1_w (32 x 256 thr) ----------------
__global__ __launch_bounds__(256) void k_mlp(
        const float* __restrict__ S, const float* __restrict__ chainv,
        const float2* __restrict__ q1, const float2* __restrict__ q2,
        const float2* __restrict__ p3, const float* __restrict__ dinv,
        const float* __restrict__ gcn_b,
        const float* __restrict__ r1_w, const float* __restrict__ r1_b,
        const float* __restrict__ r2_w, const float* __restrict__ r2_b,
        float* __restrict__ out, int N) {
    __shared__ float rw[128 * 128];       // 64 KB
    __shared__ float pl[128], red[128];
    __shared__ float cnts[NGRAPH];
    __shared__ float r4[4 * 128];
    int tid = threadIdx.x;
    int g = blockIdx.x;
    {
        const float4* Rg = (const float4*)r1_w;
        float4* Rs = (float4*)rw;
#pragma unroll
        for (int i = 0; i < 16; i++) Rs[tid + i * 256] = Rg[tid + i * 256];
    }
    if (tid < NGRAPH) cnts[tid] = S[tid];
    __syncthreads();
    int r0 = 0;
    for (int i = 0; i < g; i++) r0 += (int)cnts[i];
    int cnt = (int)cnts[g];
    int r1 = r0 + cnt;
    float su1 = 0.f, su2 = 0.f, su3 = 0.f, sv3 = 0.f;
    for (int n = r0 + tid; n < r1; n += 256) {
        float inv = 1.0f / dinv[n];
        su1 += q1[n].y * inv;
        su2 += q2[n].y * inv;
        float2 p = p3[n];
        su3 += p.y; sv3 += p.x;
    }
#pragma unroll
    for (int m = 32; m > 0; m >>= 1) {
        su1 += __shfl_xor(su1, m);
        su2 += __shfl_xor(su2, m);
        su3 += __shfl_xor(su3, m);
        sv3 += __shfl_xor(sv3, m);
    }
    int wv = tid >> 6;
    if ((tid & 63) == 0) {
        r4[wv] = su1; r4[4 + wv] = su2; r4[8 + wv] = su3; r4[12 + wv] = sv3;
    }
    __syncthreads();
    su1 = r4[0] + r4[1] + r4[2] + r4[3];
    su2 = r4[4] + r4[5] + r4[6] + r4[7];
    su3 = r4[8] + r4[9] + r4[10] + r4[11];
    sv3 = r4[12] + r4[13] + r4[14] + r4[15];
    const float* b3 = gcn_b + 2 * 128;
    if (tid < 128)
        pl[tid] = sv3 * chainv[tid] + su3 * chainv[128 + tid] + su2 * chainv[256 + tid]
                + su1 * chainv[384 + tid] + (float)cnt * b3[tid];
    __syncthreads();
    int j = tid & 127, half = tid >> 7;
    float acc = 0.f;
#pragma unroll
    for (int kk = 0; kk < 64; kk++) {
        int k = half * 64 + kk;
        acc += pl[k] * rw[k * 128 + j];
    }
    r4[half * 128 + j] = acc;
    __syncthreads();
    if (tid < 128) {
        float a = r4[tid] + r4[128 + tid] + r1_b[tid];
        red[tid] = tanhf(a) * r2_w[tid];
    }
    __syncthreads();
    for (int sft = 64; sft > 0; sft >>= 1) {
        if (tid < sft) red[tid] += red[tid + sft];
        __syncthreads();
    }
    if (tid == 0) out[g] = red[0] + r2_b[0];
}

extern "C" void kernel_launch(void* const* d_in, const int* in_sizes, int n_in,
                              void* d_out, int out_size, void* d_ws, size_t ws_size,
                              hipStream_t stream) {
    const float* x     = (const float*)d_in[0];
    const int*   eidx  = (const int*)d_in[1];
    const int*   batch = (const int*)d_in[2];
    const float* lin_w = (const float*)d_in[3];
    const float* lin_b = (const float*)d_in[4];
    const float* gcn_w = (const float*)d_in[5];
    const float* gcn_b = (const float*)d_in[6];
    const float* r1_w  = (const float*)d_in[7];
    const float* r1_b  = (const float*)d_in[8];
    const float* r2_w  = (const float*)d_in[9];
    const float* r2_b  = (const float*)d_in[10];

    const int N = in_sizes[0];
    const int E = in_sizes[1] / 2;
    const int* src = eidx;
    const int* dst = eidx + E;
    const int NB = (N + 255) / 256;  // 196 buckets

    // workspace layout: 8B-aligned types first, 4B, then 2B csr last
    // q arrays sized N+2 (entry N is the gather sentinel, +1 spare for alignment)
    char* w = (char*)d_ws;
    float2* q0      = (float2*)w; w += (size_t)(N + 2) * 8;
    float2* q1      = (float2*)w; w += (size_t)(N + 2) * 8;
    float2* q2      = (float2*)w; w += (size_t)(N + 2) * 8;
    float2* p3      = (float2*)w; w += (size_t)(N + 2) * 8;
    unsigned int* packed = (unsigned int*)w; w += (size_t)256 * CAP * 4;
    int*    offs    = (int*)w;    w += (size_t)N * 4;
    int*    deg     = (int*)w;    w += (size_t)N * 4;
    float*  dinv    = (float*)w;  w += (size_t)N * 4;
    int*    gcursor = (int*)w;    w += 256 * 4;
    float*  S       = (float*)w;  w += 64 * 4;
    float*  chainv  = (float*)w;  w += 512 * 4;
    unsigned short* csr = (unsigned short*)w; w += (size_t)256 * CAP * 2 + 256;

    // single memset covers gcursor (1024 B) + S (256 B), contiguous
    hipMemsetAsync(gcursor, 0, 256 * 4 + 64 * 4, stream);

    k_part<<<(E + EPB - 1) / EPB, 256, 0, stream>>>(src, dst, gcursor, packed, E);
    k_bucket<<<NB, 256, 0, stream>>>(packed, gcursor, x, batch, offs, deg, dinv,
                                     q0, q1, q2, csr, S, N);

    int hop_blocks = (N + 15) / 16;
    k_hop<1><<<hop_blocks, 256, 0, stream>>>(q0, q1, csr, offs, deg, dinv, N);
    k_hop<1><<<hop_blocks, 256, 0, stream>>>(q1, q2, csr, offs, deg, dinv, N);
    k_hop<0><<<hop_blocks, 256, 0, stream>>>(q2, p3, csr, offs, deg, dinv, N);

    k_chain<<<1, 1024, 0, stream>>>(lin_w, lin_b, gcn_w, gcn_b, chainv);
    k_mlp<<<NGRAPH, 256, 0, stream>>>(S, chainv, q1, q2, p3, dinv, gcn_b,
                                      r1_w, r1_b, r2_w, r2_b, (float*)d_out, N);
}